// Round 1
// baseline (486.840 us; speedup 1.0000x reference)
//
#include <hip/hip_runtime.h>

// Unpool (conv_transpose2d with single-1 depthwise kernel), stride 2.
// in:  (8, 256, 112, 112) fp32
// out: (8, 256, 224, 224) fp32, out[:,:,::2,::2] = in, else 0.
//
// Input-driven: one thread per input float4. Writes 2 float4 (data
// interleaved with zeros) to the even output row and 2 zero float4 to the
// odd row. out_row = 2*row_in holds exactly because H_out = 2*H_in and
// W-rows flatten as bc*H + h.

constexpr int W_IN  = 112;
constexpr int W_OUT = 224;

__global__ __launch_bounds__(256) void unpool_kernel(
    const float* __restrict__ in, float* __restrict__ out, int n_vec4)
{
    int idx = blockIdx.x * blockDim.x + threadIdx.x;
    if (idx >= n_vec4) return;

    int inflat = idx << 2;                 // input element index (multiple of 4)
    int row_in = inflat / W_IN;            // = (b*C + c)*112 + h
    int col    = inflat - row_in * W_IN;   // multiple of 4

    const float4 v = *reinterpret_cast<const float4*>(in + inflat);

    // out_row = (b*C + c)*224 + 2*h = 2*row_in
    int out_base = 2 * row_in * W_OUT + 2 * col;   // 16B-aligned

    float4* o_even = reinterpret_cast<float4*>(out + out_base);
    float4* o_odd  = reinterpret_cast<float4*>(out + out_base + W_OUT);

    o_even[0] = make_float4(v.x, 0.0f, v.y, 0.0f);
    o_even[1] = make_float4(v.z, 0.0f, v.w, 0.0f);
    o_odd[0]  = make_float4(0.0f, 0.0f, 0.0f, 0.0f);
    o_odd[1]  = make_float4(0.0f, 0.0f, 0.0f, 0.0f);
}

extern "C" void kernel_launch(void* const* d_in, const int* in_sizes, int n_in,
                              void* d_out, int out_size, void* d_ws, size_t ws_size,
                              hipStream_t stream)
{
    const float* x = (const float*)d_in[0];
    float* out     = (float*)d_out;

    int n_vec4 = in_sizes[0] / 4;          // 6,422,528
    int block  = 256;
    int grid   = (n_vec4 + block - 1) / block;

    unpool_kernel<<<grid, block, 0, stream>>>(x, out, n_vec4);
}

// Round 2
// 457.789 us; speedup vs baseline: 1.0635x; 1.0635x over previous
//
#include <hip/hip_runtime.h>

// Unpool (conv_transpose2d, single-1 depthwise kernel), stride 2.
// in:  (8, 256, 112, 112) fp32;  out: (8, 256, 224, 224) fp32,
// out[:,:,::2,::2] = in, rest 0.
//
// Lane-dense mapping: thread t -> input row r=t/56, out-float4 j=t%56.
//   load  float2 @ in  + 2t          (fully contiguous across wave, 8 B/lane)
//   store float4 @ out + 448r + 4j   (runs of 56 contiguous float4, 16 B/lane)
//   store zero   @ out + 448r + 224 + 4j  (odd output row, same density)
// Every output element written exactly once (d_out is poisoned 0xAA).

__global__ __launch_bounds__(256) void unpool_dense(
    const float* __restrict__ in, float* __restrict__ out, unsigned n)
{
    unsigned t = blockIdx.x * blockDim.x + threadIdx.x;
    if (t >= n) return;

    unsigned r = t / 56u;          // input flat row (b*C + c)*112 + h
    unsigned j = t - r * 56u;      // output float4 index within row

    const float2 v = *reinterpret_cast<const float2*>(in + 2u * t);

    float* base = out + 448u * r + 4u * j;       // even output row
    *reinterpret_cast<float4*>(base)       = make_float4(v.x, 0.0f, v.y, 0.0f);
    *reinterpret_cast<float4*>(base + 224) = make_float4(0.0f, 0.0f, 0.0f, 0.0f);
}

extern "C" void kernel_launch(void* const* d_in, const int* in_sizes, int n_in,
                              void* d_out, int out_size, void* d_ws, size_t ws_size,
                              hipStream_t stream)
{
    const float* x = (const float*)d_in[0];
    float* out     = (float*)d_out;

    unsigned n = (unsigned)in_sizes[0] / 2u;   // 12,845,056 threads
    int block  = 256;
    int grid   = (int)((n + block - 1) / block);

    unpool_dense<<<grid, block, 0, stream>>>(x, out, n);
}